// Round 4
// baseline (999.697 us; speedup 1.0000x reference)
//
#include <hip/hip_runtime.h>
#include <cstdint>
#include <cstddef>

// Problem constants (fixed by reference)
#define N_SEQ 64
#define T_LEN 256
#define VOCAB 32000
#define EDIM  256
#define KS    128          // hidden states
#define KK    16384        // KS*KS
#define MROWS 16384        // padded (t,n) rows for GEMM (real: 255*64 = 16320)
#define MREAL 16320
#define GPART 16           // srow partial groups (by-split in gemm grid)

typedef short  short8  __attribute__((ext_vector_type(8)));
typedef float  floatx4 __attribute__((ext_vector_type(4)));

static __device__ __forceinline__ unsigned short f2bf(float f) {
  unsigned u = __float_as_uint(f);
  u += 0x7fffu + ((u >> 16) & 1u);          // RNE
  return (unsigned short)(u >> 16);
}
static __device__ __forceinline__ float bf2f(unsigned short h) {
  return __uint_as_float(((unsigned)h) << 16);
}

static __device__ __forceinline__ void gl_lds16(const void* gptr, void* lptr) {
  // async global->LDS, 16B per lane; LDS dest = wave-uniform base + lane*16
  __builtin_amdgcn_global_load_lds(
      (const __attribute__((address_space(1))) void*)gptr,
      (__attribute__((address_space(3))) void*)lptr, 16, 0, 0);
}

// ---------------- start-distribution log_softmax -------------------------
__global__ __launch_bounds__(128) void k_prep(const float* sw, const float* sb, float* pre0) {
  __shared__ float vals[KS];
  __shared__ float MM, LS;
  int tid = threadIdx.x;
  float v = sw[tid] + sb[tid];
  vals[tid] = v;
  __syncthreads();
  if (tid == 0) { float m = vals[0]; for (int i = 1; i < KS; ++i) m = fmaxf(m, vals[i]); MM = m; }
  __syncthreads();
  float e = __expf(v - MM);
  vals[tid] = e;
  __syncthreads();
  if (tid == 0) { float s = 0.f; for (int i = 0; i < KS; ++i) s += vals[i]; LS = MM + __logf(s); }
  __syncthreads();
  pre0[tid] = v - LS;
}

// ------- trans_w fp32 -> bf16, ROW-PERMUTED: row' = (j)*128 + (i) --------
// original row = i*128 + j  (tran[i][j]); permuted so GEMM's c-dim is j-major
__global__ __launch_bounds__(256) void k_transcvt(const float* tw, unsigned short* tb) {
  int idx = blockIdx.x * 256 + threadIdx.x;          // over float4 groups
  if (idx >= (KK * EDIM) / 4) return;
  int row = idx >> 6, e4 = idx & 63;
  int rowp = ((row & 127) << 7) | (row >> 7);
  float4 v = *(const float4*)&tw[(size_t)idx * 4];
  unsigned h0 = f2bf(v.x), h1 = f2bf(v.y), h2 = f2bf(v.z), h3 = f2bf(v.w);
  uint2 o; o.x = h0 | (h1 << 16); o.y = h2 | (h3 << 16);
  *(uint2*)&tb[(size_t)rowp * EDIM + e4 * 4] = o;
}

// ---------------- gather token embeddings -> bf16 rows m = t*64+n --------
__global__ __launch_bounds__(256) void k_embed(const int* x, const float* ew, unsigned short* exb) {
  int m = blockIdx.x, e = threadIdx.x;
  int t = m >> 6, n = m & 63;
  float v = 0.f;
  if (m < MREAL) { int tok = x[n * T_LEN + t]; v = ew[(size_t)tok * EDIM + e]; }
  exb[(size_t)m * EDIM + e] = f2bf(v);
}

// ---------------- emission logits C[k][v] = ecl[k] . emit_w[v] -----------
__global__ __launch_bounds__(256) void k_emitlogits(const float* ecl, const float* emw, float* C) {
  int v0 = blockIdx.x * 64, k0 = blockIdx.y * 64;
  int tid = threadIdx.x;
  __shared__ alignas(16) float At[64 * 17];
  __shared__ alignas(16) float Bt[64 * 17];
  int tx = tid & 15, ty = tid >> 4;
  int r = tid >> 2, q = tid & 3;
  float acc[4][4] = {};
  for (int d0 = 0; d0 < KS; d0 += 16) {
    float4 av = *(const float4*)&ecl[(size_t)(k0 + r) * KS + d0 + q * 4];
    float4 bv = *(const float4*)&emw[(size_t)(v0 + r) * KS + d0 + q * 4];
    __syncthreads();
    At[r * 17 + q * 4 + 0] = av.x; At[r * 17 + q * 4 + 1] = av.y;
    At[r * 17 + q * 4 + 2] = av.z; At[r * 17 + q * 4 + 3] = av.w;
    Bt[r * 17 + q * 4 + 0] = bv.x; Bt[r * 17 + q * 4 + 1] = bv.y;
    Bt[r * 17 + q * 4 + 2] = bv.z; Bt[r * 17 + q * 4 + 3] = bv.w;
    __syncthreads();
    #pragma unroll
    for (int dd = 0; dd < 16; ++dd) {
      float a[4], b[4];
      #pragma unroll
      for (int i = 0; i < 4; ++i) a[i] = At[(ty * 4 + i) * 17 + dd];
      #pragma unroll
      for (int i = 0; i < 4; ++i) b[i] = Bt[(tx * 4 + i) * 17 + dd];
      #pragma unroll
      for (int i = 0; i < 4; ++i)
        #pragma unroll
        for (int jj = 0; jj < 4; ++jj) acc[i][jj] += a[i] * b[jj];
    }
  }
  #pragma unroll
  for (int i = 0; i < 4; ++i) {
    float4 o; o.x = acc[i][0]; o.y = acc[i][1]; o.z = acc[i][2]; o.w = acc[i][3];
    *(float4*)&C[(size_t)(k0 + ty * 4 + i) * VOCAB + v0 + tx * 4] = o;
  }
}

// ---------------- per-cluster lse over vocab -----------------------------
__global__ __launch_bounds__(256) void k_lsec(const float* C, float* lseC) {
  int k = blockIdx.x, tid = threadIdx.x;
  __shared__ float sm[4], ss[4];
  const float* row = C + (size_t)k * VOCAB;
  float m = -1e30f;
  for (int v = tid; v < VOCAB; v += 256) m = fmaxf(m, row[v]);
  #pragma unroll
  for (int s = 1; s < 64; s <<= 1) m = fmaxf(m, __shfl_xor(m, s));
  if ((tid & 63) == 0) sm[tid >> 6] = m;
  __syncthreads();
  m = fmaxf(fmaxf(sm[0], sm[1]), fmaxf(sm[2], sm[3]));
  float sum = 0.f;
  for (int v = tid; v < VOCAB; v += 256) sum += __expf(row[v] - m);
  #pragma unroll
  for (int s = 1; s < 64; s <<= 1) sum += __shfl_xor(sum, s);
  if ((tid & 63) == 0) ss[tid >> 6] = sum;
  __syncthreads();
  if (tid == 0) lseC[k] = m + __logf(ss[0] + ss[1] + ss[2] + ss[3]);
}

// ---------------- gather emission log-probs emis[n][t][k] ----------------
__global__ __launch_bounds__(128) void k_emis(const int* x, const float* C, const float* lseC, float* emis) {
  int t = blockIdx.x + 1;          // 1..255
  int n = blockIdx.y;
  int k = threadIdx.x;
  int w = x[n * T_LEN + t];
  emis[(size_t)((n << 8) + t) * KS + k] = C[(size_t)k * VOCAB + w] - lseC[k];
}

// ---- big GEMM chunk (permuted c-dim): S[mloc][j*128 + swz(i)] = exp(.) --
// by-loop of 8 j-tiles inside block; srow partials accumulate in registers
// (each (m,i) element owned by exactly one lane across all by iterations).
__global__ __launch_bounds__(256, 2) void k_gemm(const unsigned short* exb, const unsigned short* trb,
                                                 unsigned char* S, float* srowP, int m_base, int Rcap) {
  int bx = blockIdx.x, grp = blockIdx.y;       // grp 0..15
  int tid = threadIdx.x, wv = tid >> 6, ln = tid & 63;
  int wc = wv & 1, wm = wv >> 1;
  __shared__ alignas(16) unsigned short As[128 * 64];
  __shared__ alignas(16) unsigned short Bs[128 * 64];
  int m0 = m_base + bx * 128;                  // global row base
  int lr = ln & 15, lk = (ln >> 4) * 8;
  int lg = ln >> 4;                            // 0..3, epilogue reg-group
  floatx4 sacc[4][4] = {};                     // per-element srow partials
  for (int byi = 0; byi < 8; ++byi) {
    int by = grp * 8 + byi;                    // j-tile index
    int c0 = by * 128;
    floatx4 acc[4][4] = {};                    // [fc][fm]; Cᵀ: rows=c(=i), cols=m
    for (int k0 = 0; k0 < EDIM; k0 += 64) {
      #pragma unroll
      for (int r = 0; r < 4; ++r) {
        int chunk = (wv * 4 + r) * 64 + ln;    // 16B chunk id in 16KB tile
        int row = chunk >> 3, c8 = chunk & 7;
        gl_lds16(&exb[(size_t)(m0 + row) * EDIM + k0 + c8 * 8], &As[(wv * 4 + r) * 512]);
        gl_lds16(&trb[(size_t)(c0 + row) * EDIM + k0 + c8 * 8], &Bs[(wv * 4 + r) * 512]);
      }
      __syncthreads();
      #pragma unroll
      for (int kk = 0; kk < 64; kk += 32) {
        short8 af[4], bf[4];
        #pragma unroll
        for (int f = 0; f < 4; ++f)
          af[f] = *(const short8*)&As[(wm * 64 + f * 16 + lr) * 64 + kk + lk];
        #pragma unroll
        for (int f = 0; f < 4; ++f)
          bf[f] = *(const short8*)&Bs[(wc * 64 + f * 16 + lr) * 64 + kk + lk];
        #pragma unroll
        for (int fc = 0; fc < 4; ++fc)
          #pragma unroll
          for (int fm = 0; fm < 4; ++fm)
            acc[fc][fm] = __builtin_amdgcn_mfma_f32_16x16x32_bf16(bf[fc], af[fm], acc[fc][fm], 0, 0, 0);
      }
      __syncthreads();
    }
    // epilogue: exp, fp8 pack into LDS tile (XOR bank swizzle), srow regs
    unsigned char* Ts = (unsigned char*)As;    // reuse 16 KB
    #pragma unroll
    for (int fc = 0; fc < 4; ++fc) {
      #pragma unroll
      for (int fm = 0; fm < 4; ++fm) {
        floatx4 a = acc[fc][fm];
        float e0 = __expf(a[0]), e1 = __expf(a[1]), e2 = __expf(a[2]), e3 = __expf(a[3]);
        int p = __builtin_amdgcn_cvt_pk_fp8_f32(e0, e1, 0, 0);
        p = __builtin_amdgcn_cvt_pk_fp8_f32(e2, e3, p, 1);
        int mloc = wm * 64 + fm * 16 + lr;
        int cl = wc * 64 + fc * 16 + lg * 4;   // cl = i (tile-local)
        *(int*)&Ts[mloc * 128 + (cl ^ ((mloc & 7) << 4))] = p;
        sacc[fc][fm][0] += e0; sacc[fc][fm][1] += e1;
        sacc[fc][fm][2] += e2; sacc[fc][fm][3] += e3;
      }
    }
    __syncthreads();                           // Ts ready
    // store: S[m][c0 + s*16] holds i-block (s ^ (by&7))  (global XOR swizzle)
    #pragma unroll
    for (int r = 0; r < 4; ++r) {
      int seg = r * 256 + tid;                 // 1024 x 16B segments
      int mloc = seg >> 3, s = seg & 7;
      int b = s ^ (by & 7);
      uint4 v = *(const uint4*)&Ts[mloc * 128 + ((b ^ (mloc & 7)) << 4)];
      *(uint4*)&S[(size_t)(bx * 128 + mloc) * KK + c0 + s * 16] = v;
    }
    __syncthreads();                           // Ts dead before next staging
  }
  // srowP[grp][mloc][i] = partial sum over this block's 8 j values
  #pragma unroll
  for (int fc = 0; fc < 4; ++fc) {
    #pragma unroll
    for (int fm = 0; fm < 4; ++fm) {
      int mloc = bx * 128 + wm * 64 + fm * 16 + lr;
      int i = wc * 64 + fc * 16 + lg * 4;
      *(floatx4*)&srowP[((size_t)grp * Rcap + mloc) * KS + i] = sacc[fc][fm];
    }
  }
}

// ---- combine srow partials -> srowR[m][i] = 1/sum (global m indexing) ---
__global__ __launch_bounds__(256) void k_comb(const float* srowP, float* srowR,
                                              int m_base, int Rcap, int rows) {
  int id = blockIdx.x * 256 + threadIdx.x;
  if (id >= rows * KS) return;
  float s = 0.f;
  #pragma unroll
  for (int g = 0; g < GPART; ++g) s += srowP[(size_t)g * Rcap * KS + id];
  srowR[(size_t)m_base * KS + id] = 1.0f / s;
}

// ---------------- sequential forward scan chunk, one block per sequence --
// permuted+swizzled S: row j, 16B block s holds i-block (s ^ (j&7)).
// triple-buffered global_load_lds staging (2 ahead), bf16 u broadcast,
// ds_add_f32 partial sums (triple-buffered), 2 barriers/step.
__global__ __launch_bounds__(1024) void k_scan(const unsigned char* S, const float* srowR,
                                               const float* emis, const float* pre0,
                                               float* alphaG, float* nll, int t0, int tc) {
  int n = blockIdx.x, tid = threadIdx.x;
  int j = tid & 127, gi = tid >> 7;        // gi 0..7 (16-i slice)
  int wv = tid >> 6, ln = tid & 63;
  __shared__ alignas(16) unsigned char Sb[3][KK];
  __shared__ alignas(16) unsigned short uh[KS];   // bf16 u
  __shared__ float sums[3][KS];
  int t1 = t0 + tc;
  const float* a0 = (t0 == 1) ? pre0 : (alphaG + (size_t)n * KS);
  float pre_j = a0[j];
  float M     = a0[0];
  float rs = srowR[(size_t)((t0 - 1) * 64 + n) * KS + j];
  float u0 = __expf(pre_j - M) * rs;
  if (gi == 0) uh[j] = f2bf(u0);
  if (tid < 384) ((float*)sums)[tid] = 0.f;
  // stage tiles t0, t0+1
  gl_lds16(&S[(size_t)n * KK + (wv << 10) + (ln << 4)], &Sb[0][wv << 10]);
  if (tc > 1)
    gl_lds16(&S[(size_t)(64 + n) * KK + (wv << 10) + (ln << 4)], &Sb[1][wv << 10]);
  float em_n = 0.f, em0_n = 0.f, rs_n = 0.f;
  for (int t = t0; t < t1; ++t) {
    int r3 = (t - t0) % 3;
    __syncthreads();                       // B1: tile t + sums(t-1) + uh ready
    if (t > t0) {
      int sp = (r3 + 2) % 3;
      float cj = sums[sp][j];
      float c0 = sums[sp][0];
      pre_j = M + __logf(cj) + em_n;       // em_n = emis[t-1]
      float Mn = M + __logf(c0) + em0_n;
      float u = __expf(pre_j - Mn) * rs_n; // rs_n = rs(t)
      M = Mn;
      if (gi == 0) uh[j] = f2bf(u);
    }
    if (wv >= 14) sums[(r3 + 1) % 3][tid & 127] = 0.f;   // zero for step t+1
    __syncthreads();                       // B2: uh(t) + zeroes visible
    if (t + 2 < t1)
      gl_lds16(&S[(size_t)((t + 2 - t0) * 64 + n) * KK + (wv << 10) + (ln << 4)],
               &Sb[(r3 + 2) % 3][wv << 10]);
    // prefetch for α(t+1)
    em_n  = emis[(size_t)((n << 8) + t) * KS + j];
    em0_n = emis[(size_t)((n << 8) + t) * KS];
    if (t + 1 < t1) rs_n = srowR[(size_t)(t * 64 + n) * KS + j];
    // matvec: 16 i-values for row j, one b128
    const unsigned char* sc = Sb[r3];
    uint4 sv = *(const uint4*)&sc[(j << 7) + ((gi ^ (j & 7)) << 4)];
    const uint4* up4 = (const uint4*)&uh[gi << 4];
    uint4 ua = up4[0], ub = up4[1];
    unsigned w0[4] = {sv.x, sv.y, sv.z, sv.w};
    unsigned hh[8] = {ua.x, ua.y, ua.z, ua.w, ub.x, ub.y, ub.z, ub.w};
    float a = 0.f;
    #pragma unroll
    for (int q = 0; q < 4; ++q) {
      float ulo0 = __uint_as_float(hh[q * 2] << 16);
      float uhi0 = __uint_as_float(hh[q * 2] & 0xffff0000u);
      float ulo1 = __uint_as_float(hh[q * 2 + 1] << 16);
      float uhi1 = __uint_as_float(hh[q * 2 + 1] & 0xffff0000u);
      a += __builtin_amdgcn_cvt_f32_fp8((int)w0[q], 0) * ulo0;
      a += __builtin_amdgcn_cvt_f32_fp8((int)w0[q], 1) * uhi0;
      a += __builtin_amdgcn_cvt_f32_fp8((int)w0[q], 2) * ulo1;
      a += __builtin_amdgcn_cvt_f32_fp8((int)w0[q], 3) * uhi1;
    }
    atomicAdd(&sums[r3][j], a);
  }
  // final alpha update (consumes sums of last step)
  __syncthreads();
  {
    int sp = (tc - 1) % 3;
    float cj = sums[sp][j];
    float c0 = sums[sp][0];
    pre_j = M + __logf(cj) + em_n;
    M     = M + __logf(c0) + em0_n;
  }
  if (gi == 0) alphaG[(size_t)n * KS + j] = pre_j;
  if (t1 == T_LEN) {
    float m2 = (gi == 0) ? pre_j : -1e30f;
    #pragma unroll
    for (int s = 1; s < 64; s <<= 1) m2 = fmaxf(m2, __shfl_xor(m2, s));
    __syncthreads();
    if (ln == 0) sums[0][wv] = m2;
    __syncthreads();
    float mm = sums[0][0];
    #pragma unroll
    for (int k2 = 1; k2 < 16; ++k2) mm = fmaxf(mm, sums[0][k2]);
    float e = (gi == 0) ? __expf(pre_j - mm) : 0.f;
    #pragma unroll
    for (int s = 1; s < 64; s <<= 1) e += __shfl_xor(e, s);
    __syncthreads();
    if (ln == 0) sums[1][wv] = e;
    __syncthreads();
    if (tid == 0) {
      float s = 0.f;
      for (int k2 = 0; k2 < 16; ++k2) s += sums[1][k2];
      nll[n] = mm + __logf(s);
    }
  }
}

// ---------------- final: out = -mean(nll) --------------------------------
__global__ __launch_bounds__(64) void k_final(const float* nll, float* out) {
  int tid = threadIdx.x;
  float v = nll[tid];
  #pragma unroll
  for (int s = 1; s < 64; s <<= 1) v += __shfl_xor(v, s);
  if (tid == 0) out[0] = -v / 64.0f;
}

extern "C" void kernel_launch(void* const* d_in, const int* in_sizes, int n_in,
                              void* d_out, int out_size, void* d_ws, size_t ws_size,
                              hipStream_t stream) {
  const int*   x       = (const int*)d_in[0];
  const float* embed_w = (const float*)d_in[1];
  const float* trans_w = (const float*)d_in[2];
  const float* start_w = (const float*)d_in[3];
  const float* start_b = (const float*)d_in[4];
  const float* ecl     = (const float*)d_in[5];
  const float* emw     = (const float*)d_in[6];

  char* w = (char*)d_ws;
  size_t off = 0;
  auto alloc = [&](size_t bytes) -> char* {
    char* p = w + off;
    off = (off + bytes + 255) & ~(size_t)255;
    return p;
  };
  float*          pre0   = (float*)alloc(KS * 4);
  float*          lseC   = (float*)alloc(KS * 4);
  float*          nll    = (float*)alloc(N_SEQ * 4);
  float*          alphaG = (float*)alloc((size_t)N_SEQ * KS * 4);
  unsigned short* trb    = (unsigned short*)alloc((size_t)KK * EDIM * 2);     // 8.39 MB (permuted)
  unsigned short* exb    = (unsigned short*)alloc((size_t)MROWS * EDIM * 2);  // 8.39 MB
  float*          emis   = (float*)alloc((size_t)N_SEQ * T_LEN * KS * 4);     // 8.39 MB
  float*          srowR  = (float*)alloc((size_t)MROWS * KS * 4);             // 8.39 MB
  // chunk region: S chunk + srowP partials; also aliases transient C
  char* region = w + off;
  size_t avail = (ws_size > off) ? (ws_size - off) : 0;
  float* C = (float*)region;                       // 16.38 MB transient

  // per chunk of Tc steps: R = Tc*64 rows: S = R*16384 B, srowP = GPART*R*KS*4 = R*8192 B
  int Tc = 2;
  for (int c = 2; c <= 64; c += 2)
    if ((size_t)c * 64 * (KK + GPART * KS * 4 / 2) <= avail) Tc = c;   // c*64*(16384+8192... wait
  // recompute precisely: bytes = R*16384 + R*8192 = R*24576
  Tc = 2;
  for (int c = 2; c <= 64; c += 2)
    if ((size_t)c * 64 * 24576 <= avail) Tc = c;
  int Rcap = Tc * 64;
  unsigned char* S     = (unsigned char*)region;
  float*         srowP = (float*)(region + (size_t)Rcap * KK);

  hipLaunchKernelGGL(k_prep,       dim3(1),        dim3(128), 0, stream, start_w, start_b, pre0);
  hipLaunchKernelGGL(k_transcvt,   dim3(4096),     dim3(256), 0, stream, trans_w, trb);
  hipLaunchKernelGGL(k_embed,      dim3(16384),    dim3(256), 0, stream, x, embed_w, exb);
  hipLaunchKernelGGL(k_emitlogits, dim3(500, 2),   dim3(256), 0, stream, ecl, emw, C);
  hipLaunchKernelGGL(k_lsec,       dim3(128),      dim3(256), 0, stream, C, lseC);
  hipLaunchKernelGGL(k_emis,       dim3(255, 64),  dim3(128), 0, stream, x, C, lseC, emis);

  int t0 = 1;
  while (t0 < T_LEN) {
    int tc = T_LEN - t0; if (tc > Tc) tc = Tc;
    int m_base = (t0 - 1) * 64;
    int gx = (tc * 64 + 127) / 128;
    hipLaunchKernelGGL(k_gemm, dim3(gx, GPART), dim3(256),  0, stream, exb, trb, S, srowP, m_base, Rcap);
    hipLaunchKernelGGL(k_comb, dim3(gx * 64),   dim3(256),  0, stream, srowP, srowR, m_base, Rcap, gx * 128);
    hipLaunchKernelGGL(k_scan, dim3(64),        dim3(1024), 0, stream, S, srowR, emis, pre0, alphaG, nll, t0, tc);
    t0 += tc;
  }
  hipLaunchKernelGGL(k_final, dim3(1), dim3(64), 0, stream, nll, (float*)d_out);
}

// Round 5
// 697.077 us; speedup vs baseline: 1.4341x; 1.4341x over previous
//
#include <hip/hip_runtime.h>
#include <cstdint>
#include <cstddef>

// Problem constants (fixed by reference)
#define N_SEQ 64
#define T_LEN 256
#define VOCAB 32000
#define EDIM  256
#define KS    128          // hidden states
#define KK    16384        // KS*KS
#define MROWS 16384        // padded (t,n) rows for GEMM (real: 255*64 = 16320)
#define MREAL 16320
#define GPART 16           // srow partial groups (by-split in gemm grid)

typedef short  short8  __attribute__((ext_vector_type(8)));
typedef float  floatx4 __attribute__((ext_vector_type(4)));
typedef float  floatx2 __attribute__((ext_vector_type(2)));

static __device__ __forceinline__ unsigned short f2bf(float f) {
  unsigned u = __float_as_uint(f);
  u += 0x7fffu + ((u >> 16) & 1u);          // RNE
  return (unsigned short)(u >> 16);
}

static __device__ __forceinline__ float4 cvt4_fp8(unsigned w) {
  float4 r;
#if __has_builtin(__builtin_amdgcn_cvt_pk_f32_fp8)
  floatx2 lo = __builtin_amdgcn_cvt_pk_f32_fp8((int)w, false);
  floatx2 hi = __builtin_amdgcn_cvt_pk_f32_fp8((int)w, true);
  r.x = lo[0]; r.y = lo[1]; r.z = hi[0]; r.w = hi[1];
#else
  r.x = __builtin_amdgcn_cvt_f32_fp8((int)w, 0);
  r.y = __builtin_amdgcn_cvt_f32_fp8((int)w, 1);
  r.z = __builtin_amdgcn_cvt_f32_fp8((int)w, 2);
  r.w = __builtin_amdgcn_cvt_f32_fp8((int)w, 3);
#endif
  return r;
}

static __device__ __forceinline__ void gl_lds16(const void* gptr, void* lptr) {
  // async global->LDS, 16B per lane; LDS dest = wave-uniform base + lane*16
  __builtin_amdgcn_global_load_lds(
      (const __attribute__((address_space(1))) void*)gptr,
      (__attribute__((address_space(3))) void*)lptr, 16, 0, 0);
}

// ---------------- start-distribution log_softmax -------------------------
__global__ __launch_bounds__(128) void k_prep(const float* sw, const float* sb, float* pre0) {
  __shared__ float vals[KS];
  __shared__ float MM, LS;
  int tid = threadIdx.x;
  float v = sw[tid] + sb[tid];
  vals[tid] = v;
  __syncthreads();
  if (tid == 0) { float m = vals[0]; for (int i = 1; i < KS; ++i) m = fmaxf(m, vals[i]); MM = m; }
  __syncthreads();
  float e = __expf(v - MM);
  vals[tid] = e;
  __syncthreads();
  if (tid == 0) { float s = 0.f; for (int i = 0; i < KS; ++i) s += vals[i]; LS = MM + __logf(s); }
  __syncthreads();
  pre0[tid] = v - LS;
}

// ------- trans_w fp32 -> bf16, ROW-PERMUTED: row' = (j)*128 + (i) --------
// original row = i*128 + j  (tran[i][j]); permuted so GEMM's c-dim is j-major
__global__ __launch_bounds__(256) void k_transcvt(const float* tw, unsigned short* tb) {
  int idx = blockIdx.x * 256 + threadIdx.x;          // over float4 groups
  if (idx >= (KK * EDIM) / 4) return;
  int row = idx >> 6, e4 = idx & 63;
  int rowp = ((row & 127) << 7) | (row >> 7);
  float4 v = *(const float4*)&tw[(size_t)idx * 4];
  unsigned h0 = f2bf(v.x), h1 = f2bf(v.y), h2 = f2bf(v.z), h3 = f2bf(v.w);
  uint2 o; o.x = h0 | (h1 << 16); o.y = h2 | (h3 << 16);
  *(uint2*)&tb[(size_t)rowp * EDIM + e4 * 4] = o;
}

// ---------------- gather token embeddings -> bf16 rows m = t*64+n --------
__global__ __launch_bounds__(256) void k_embed(const int* x, const float* ew, unsigned short* exb) {
  int m = blockIdx.x, e = threadIdx.x;
  int t = m >> 6, n = m & 63;
  float v = 0.f;
  if (m < MREAL) { int tok = x[n * T_LEN + t]; v = ew[(size_t)tok * EDIM + e]; }
  exb[(size_t)m * EDIM + e] = f2bf(v);
}

// ---------------- emission logits C[k][v] = ecl[k] . emit_w[v] -----------
__global__ __launch_bounds__(256) void k_emitlogits(const float* ecl, const float* emw, float* C) {
  int v0 = blockIdx.x * 64, k0 = blockIdx.y * 64;
  int tid = threadIdx.x;
  __shared__ alignas(16) float At[64 * 17];
  __shared__ alignas(16) float Bt[64 * 17];
  int tx = tid & 15, ty = tid >> 4;
  int r = tid >> 2, q = tid & 3;
  float acc[4][4] = {};
  for (int d0 = 0; d0 < KS; d0 += 16) {
    float4 av = *(const float4*)&ecl[(size_t)(k0 + r) * KS + d0 + q * 4];
    float4 bv = *(const float4*)&emw[(size_t)(v0 + r) * KS + d0 + q * 4];
    __syncthreads();
    At[r * 17 + q * 4 + 0] = av.x; At[r * 17 + q * 4 + 1] = av.y;
    At[r * 17 + q * 4 + 2] = av.z; At[r * 17 + q * 4 + 3] = av.w;
    Bt[r * 17 + q * 4 + 0] = bv.x; Bt[r * 17 + q * 4 + 1] = bv.y;
    Bt[r * 17 + q * 4 + 2] = bv.z; Bt[r * 17 + q * 4 + 3] = bv.w;
    __syncthreads();
    #pragma unroll
    for (int dd = 0; dd < 16; ++dd) {
      float a[4], b[4];
      #pragma unroll
      for (int i = 0; i < 4; ++i) a[i] = At[(ty * 4 + i) * 17 + dd];
      #pragma unroll
      for (int i = 0; i < 4; ++i) b[i] = Bt[(tx * 4 + i) * 17 + dd];
      #pragma unroll
      for (int i = 0; i < 4; ++i)
        #pragma unroll
        for (int jj = 0; jj < 4; ++jj) acc[i][jj] += a[i] * b[jj];
    }
  }
  #pragma unroll
  for (int i = 0; i < 4; ++i) {
    float4 o; o.x = acc[i][0]; o.y = acc[i][1]; o.z = acc[i][2]; o.w = acc[i][3];
    *(float4*)&C[(size_t)(k0 + ty * 4 + i) * VOCAB + v0 + tx * 4] = o;
  }
}

// ---------------- per-cluster lse over vocab -----------------------------
__global__ __launch_bounds__(256) void k_lsec(const float* C, float* lseC) {
  int k = blockIdx.x, tid = threadIdx.x;
  __shared__ float sm[4], ss[4];
  const float* row = C + (size_t)k * VOCAB;
  float m = -1e30f;
  for (int v = tid; v < VOCAB; v += 256) m = fmaxf(m, row[v]);
  #pragma unroll
  for (int s = 1; s < 64; s <<= 1) m = fmaxf(m, __shfl_xor(m, s));
  if ((tid & 63) == 0) sm[tid >> 6] = m;
  __syncthreads();
  m = fmaxf(fmaxf(sm[0], sm[1]), fmaxf(sm[2], sm[3]));
  float sum = 0.f;
  for (int v = tid; v < VOCAB; v += 256) sum += __expf(row[v] - m);
  #pragma unroll
  for (int s = 1; s < 64; s <<= 1) sum += __shfl_xor(sum, s);
  if ((tid & 63) == 0) ss[tid >> 6] = sum;
  __syncthreads();
  if (tid == 0) lseC[k] = m + __logf(ss[0] + ss[1] + ss[2] + ss[3]);
}

// ---------------- gather emission log-probs emis[n][t][k] ----------------
__global__ __launch_bounds__(128) void k_emis(const int* x, const float* C, const float* lseC, float* emis) {
  int t = blockIdx.x + 1;          // 1..255
  int n = blockIdx.y;
  int k = threadIdx.x;
  int w = x[n * T_LEN + t];
  emis[(size_t)((n << 8) + t) * KS + k] = C[(size_t)k * VOCAB + w] - lseC[k];
}

// ---- big GEMM chunk (permuted c-dim): S[mloc][j*128 + i] = exp(.) fp8 ---
// by-loop of 8 j-tiles inside block; srow partials accumulate in registers
// (each (m,i) element owned by exactly one lane across all by iterations).
__global__ __launch_bounds__(256, 2) void k_gemm(const unsigned short* exb, const unsigned short* trb,
                                                 unsigned char* S, float* srowP, int m_base, int Rcap) {
  int bx = blockIdx.x, grp = blockIdx.y;       // grp 0..15
  int tid = threadIdx.x, wv = tid >> 6, ln = tid & 63;
  int wc = wv & 1, wm = wv >> 1;
  __shared__ alignas(16) unsigned short As[128 * 64];
  __shared__ alignas(16) unsigned short Bs[128 * 64];
  int m0 = m_base + bx * 128;                  // global row base
  int lr = ln & 15, lk = (ln >> 4) * 8;
  int lg = ln >> 4;                            // 0..3, epilogue reg-group
  floatx4 sacc[4][4] = {};                     // per-element srow partials
  for (int byi = 0; byi < 8; ++byi) {
    int by = grp * 8 + byi;                    // j-tile index (j == by)
    int c0 = by * 128;
    floatx4 acc[4][4] = {};                    // [fc][fm]; Cᵀ: rows=c(=i), cols=m
    for (int k0 = 0; k0 < EDIM; k0 += 64) {
      #pragma unroll
      for (int r = 0; r < 4; ++r) {
        int chunk = (wv * 4 + r) * 64 + ln;    // 16B chunk id in 16KB tile
        int row = chunk >> 3, c8 = chunk & 7;
        gl_lds16(&exb[(size_t)(m0 + row) * EDIM + k0 + c8 * 8], &As[(wv * 4 + r) * 512]);
        gl_lds16(&trb[(size_t)(c0 + row) * EDIM + k0 + c8 * 8], &Bs[(wv * 4 + r) * 512]);
      }
      __syncthreads();
      #pragma unroll
      for (int kk = 0; kk < 64; kk += 32) {
        short8 af[4], bf[4];
        #pragma unroll
        for (int f = 0; f < 4; ++f)
          af[f] = *(const short8*)&As[(wm * 64 + f * 16 + lr) * 64 + kk + lk];
        #pragma unroll
        for (int f = 0; f < 4; ++f)
          bf[f] = *(const short8*)&Bs[(wc * 64 + f * 16 + lr) * 64 + kk + lk];
        #pragma unroll
        for (int fc = 0; fc < 4; ++fc)
          #pragma unroll
          for (int fm = 0; fm < 4; ++fm)
            acc[fc][fm] = __builtin_amdgcn_mfma_f32_16x16x32_bf16(bf[fc], af[fm], acc[fc][fm], 0, 0, 0);
      }
      __syncthreads();
    }
    // epilogue: exp, fp8 pack into LDS tile (XOR bank swizzle), srow regs
    unsigned char* Ts = (unsigned char*)As;    // reuse 16 KB
    #pragma unroll
    for (int fc = 0; fc < 4; ++fc) {
      #pragma unroll
      for (int fm = 0; fm < 4; ++fm) {
        floatx4 a = acc[fc][fm];
        float e0 = __expf(a[0]), e1 = __expf(a[1]), e2 = __expf(a[2]), e3 = __expf(a[3]);
        int p = __builtin_amdgcn_cvt_pk_fp8_f32(e0, e1, 0, 0);
        p = __builtin_amdgcn_cvt_pk_fp8_f32(e2, e3, p, 1);
        int mloc = wm * 64 + fm * 16 + lr;
        int cl = wc * 64 + fc * 16 + lg * 4;   // cl = i (tile-local)
        *(int*)&Ts[mloc * 128 + (cl ^ ((mloc & 7) << 4))] = p;
        sacc[fc][fm][0] += e0; sacc[fc][fm][1] += e1;
        sacc[fc][fm][2] += e2; sacc[fc][fm][3] += e3;
      }
    }
    __syncthreads();                           // Ts ready
    // store: natural layout S[m][j*128 + i] (swizzle only inside Ts)
    #pragma unroll
    for (int r = 0; r < 4; ++r) {
      int seg = r * 256 + tid;                 // 1024 x 16B segments
      int mloc = seg >> 3, s = seg & 7;
      uint4 v = *(const uint4*)&Ts[mloc * 128 + ((s ^ (mloc & 7)) << 4)];
      *(uint4*)&S[(size_t)(bx * 128 + mloc) * KK + c0 + s * 16] = v;
    }
    __syncthreads();                           // Ts dead before next staging
  }
  // srowP[grp][mloc][i] = partial sum over this block's 8 j values
  #pragma unroll
  for (int fc = 0; fc < 4; ++fc) {
    #pragma unroll
    for (int fm = 0; fm < 4; ++fm) {
      int mloc = bx * 128 + wm * 64 + fm * 16 + lr;
      int i = wc * 64 + fc * 16 + lg * 4;
      *(floatx4*)&srowP[((size_t)grp * Rcap + mloc) * KS + i] = sacc[fc][fm];
    }
  }
}

// ---- combine srow partials -> srowR[m][i] = 1/sum (global m indexing) ---
__global__ __launch_bounds__(256) void k_comb(const float* srowP, float* srowR,
                                              int m_base, int Rcap, int rows) {
  int id = blockIdx.x * 256 + threadIdx.x;
  if (id >= rows * KS) return;
  float s = 0.f;
  #pragma unroll
  for (int g = 0; g < GPART; ++g) s += srowP[(size_t)g * Rcap * KS + id];
  srowR[(size_t)m_base * KS + id] = 1.0f / s;
}

// ---------------- sequential forward scan chunk, one block per sequence --
// 512 threads: wave wv owns j = wv*16+(ln&15); gh = ln>>4 owns i-slice
// [gh*32, gh*32+32). S rows read straight from global into registers
// (coalesced, prefetched 1 step ahead). Reduction over gh = 2 shuffles.
// 2 barriers/step, no atomics.
__global__ __launch_bounds__(512) void k_scan(const unsigned char* S, const float* srowR,
                                              const float* emis, const float* pre0,
                                              float* alphaG, float* nll, int t0, int tc) {
  int n = blockIdx.x, tid = threadIdx.x;
  int ln = tid & 63, wv = tid >> 6;
  int j  = wv * 16 + (ln & 15);
  int gh = ln >> 4;
  __shared__ alignas(16) float uL[KS];
  __shared__ float sums[KS];
  __shared__ float red[16];
  int t1 = t0 + tc;
  const float* a0 = (t0 == 1) ? pre0 : (alphaG + (size_t)n * KS);
  float pre_j = a0[j];
  float M     = a0[0];
  float rs = srowR[(size_t)((t0 - 1) * 64 + n) * KS + j];
  float uv = __expf(pre_j - M) * rs;
  if (ln < 16) uL[j] = uv;
  size_t rowoff = (size_t)j * 128 + gh * 32;
  const unsigned char* b0 = S + (size_t)n * KK + rowoff;
  uint4 sva = *(const uint4*)(b0);
  uint4 svb = *(const uint4*)(b0 + 16);
  __syncthreads();                             // uL(t0) visible
  for (int t = t0; t < t1; ++t) {
    // prefetch emis/srow for the update at end of this iteration
    float em  = emis[(size_t)((n << 8) + t) * KS + j];
    float em0 = emis[(size_t)((n << 8) + t) * KS];
    float rsn = (t < T_LEN - 1) ? srowR[(size_t)(t * 64 + n) * KS + j] : 0.f;
    // prefetch next S row
    int tn = (t + 1 < t1) ? (t + 1 - t0) : 0;
    const unsigned char* bn = S + (size_t)(tn * 64 + n) * KK + rowoff;
    uint4 nxa = *(const uint4*)(bn);
    uint4 nxb = *(const uint4*)(bn + 16);
    // matvec: 32 i's for output state j
    float4 uu[8];
    const float4* up4 = (const float4*)&uL[gh * 32];
    #pragma unroll
    for (int q = 0; q < 8; ++q) uu[q] = up4[q];
    unsigned wd[8] = {sva.x, sva.y, sva.z, sva.w, svb.x, svb.y, svb.z, svb.w};
    float a = 0.f;
    #pragma unroll
    for (int q = 0; q < 8; ++q) {
      float4 c = cvt4_fp8(wd[q]);
      a += c.x * uu[q].x + c.y * uu[q].y + c.z * uu[q].z + c.w * uu[q].w;
    }
    a += __shfl_xor(a, 16);
    a += __shfl_xor(a, 32);
    if (ln < 16) sums[j] = a;
    __syncthreads();                           // B1: sums(t) visible
    float cj = sums[j];
    float c0 = sums[0];
    pre_j = M + __logf(cj) + em;
    M     = M + __logf(c0) + em0;
    if (t + 1 < t1) {
      float u2 = __expf(pre_j - M) * rsn;
      if (ln < 16) uL[j] = u2;
    }
    sva = nxa; svb = nxb;
    __syncthreads();                           // B2: uL(t+1) visible
  }
  if (ln < 16) alphaG[(size_t)n * KS + j] = pre_j;
  if (t1 == T_LEN) {
    float e = (ln < 16) ? __expf(pre_j - M) : 0.f;
    #pragma unroll
    for (int s = 1; s < 64; s <<= 1) e += __shfl_xor(e, s);
    if (ln == 0) red[wv] = e;
    __syncthreads();
    if (tid == 0) {
      float s = 0.f;
      for (int w8 = 0; w8 < 8; ++w8) s += red[w8];
      nll[n] = M + __logf(s);
    }
  }
}

// ---------------- final: out = -mean(nll) --------------------------------
__global__ __launch_bounds__(64) void k_final(const float* nll, float* out) {
  int tid = threadIdx.x;
  float v = nll[tid];
  #pragma unroll
  for (int s = 1; s < 64; s <<= 1) v += __shfl_xor(v, s);
  if (tid == 0) out[0] = -v / 64.0f;
}

extern "C" void kernel_launch(void* const* d_in, const int* in_sizes, int n_in,
                              void* d_out, int out_size, void* d_ws, size_t ws_size,
                              hipStream_t stream) {
  const int*   x       = (const int*)d_in[0];
  const float* embed_w = (const float*)d_in[1];
  const float* trans_w = (const float*)d_in[2];
  const float* start_w = (const float*)d_in[3];
  const float* start_b = (const float*)d_in[4];
  const float* ecl     = (const float*)d_in[5];
  const float* emw     = (const float*)d_in[6];

  char* w = (char*)d_ws;
  size_t off = 0;
  auto alloc = [&](size_t bytes) -> char* {
    char* p = w + off;
    off = (off + bytes + 255) & ~(size_t)255;
    return p;
  };
  float*          pre0   = (float*)alloc(KS * 4);
  float*          lseC   = (float*)alloc(KS * 4);
  float*          nll    = (float*)alloc(N_SEQ * 4);
  float*          alphaG = (float*)alloc((size_t)N_SEQ * KS * 4);
  unsigned short* trb    = (unsigned short*)alloc((size_t)KK * EDIM * 2);     // 8.39 MB (permuted)
  unsigned short* exb    = (unsigned short*)alloc((size_t)MROWS * EDIM * 2);  // 8.39 MB
  float*          emis   = (float*)alloc((size_t)N_SEQ * T_LEN * KS * 4);     // 8.39 MB
  float*          srowR  = (float*)alloc((size_t)MROWS * KS * 4);             // 8.39 MB
  // chunk region: S chunk + srowP partials; also aliases transient C
  // (emission logits, dead before first k_gemm).
  char* region = w + off;
  size_t avail = (ws_size > off) ? (ws_size - off) : 0;
  float* C = (float*)region;                       // 16.38 MB transient

  // per chunk of Tc steps: R = Tc*64 rows; bytes = R*(16384 + 8192)
  int Tc = 2;
  for (int c = 2; c <= 64; c += 2)
    if ((size_t)c * 64 * 24576 <= avail) Tc = c;
  int Rcap = Tc * 64;
  unsigned char* S     = (unsigned char*)region;
  float*         srowP = (float*)(region + (size_t)Rcap * KK);

  hipLaunchKernelGGL(k_prep,       dim3(1),        dim3(128), 0, stream, start_w, start_b, pre0);
  hipLaunchKernelGGL(k_transcvt,   dim3(4096),     dim3(256), 0, stream, trans_w, trb);
  hipLaunchKernelGGL(k_embed,      dim3(16384),    dim3(256), 0, stream, x, embed_w, exb);
  hipLaunchKernelGGL(k_emitlogits, dim3(500, 2),   dim3(256), 0, stream, ecl, emw, C);
  hipLaunchKernelGGL(k_lsec,       dim3(128),      dim3(256), 0, stream, C, lseC);
  hipLaunchKernelGGL(k_emis,       dim3(255, 64),  dim3(128), 0, stream, x, C, lseC, emis);

  int t0 = 1;
  while (t0 < T_LEN) {
    int tc = T_LEN - t0; if (tc > Tc) tc = Tc;
    int m_base = (t0 - 1) * 64;
    int gx = (tc * 64 + 127) / 128;
    hipLaunchKernelGGL(k_gemm, dim3(gx, GPART), dim3(256), 0, stream, exb, trb, S, srowP, m_base, Rcap);
    hipLaunchKernelGGL(k_comb, dim3(gx * 64),   dim3(256), 0, stream, srowP, srowR, m_base, Rcap, gx * 128);
    hipLaunchKernelGGL(k_scan, dim3(64),        dim3(512), 0, stream, S, srowR, emis, pre0, alphaG, nll, t0, tc);
    t0 += tc;
  }
  hipLaunchKernelGGL(k_final, dim3(1), dim3(64), 0, stream, nll, (float*)d_out);
}